// Round 9
// baseline (2582.540 us; speedup 1.0000x reference)
//
#include <hip/hip_runtime.h>

typedef _Float16 f16;
typedef _Float16 f16x2 __attribute__((ext_vector_type(2)));
typedef _Float16 f16x8 __attribute__((ext_vector_type(8)));
typedef _Float16 f16x4 __attribute__((ext_vector_type(4)));
typedef float f32x4 __attribute__((ext_vector_type(4)));

#define L2E 1.4426950408889634f
#define K2E 2.8853900817779268f

// ---- workspace layout (bytes)
#define O_PQV   0UL            // f32 [16384][512]  (aliased by GIH2C later)
#define O_GIH2C 0UL            // f16 [16384][1024]
#define O_CTX   33554432UL     // f16 [16384][256]; after last gemm -> tagged decp (16MB, spans CTX+ENCF)
#define O_ENCF  41943040UL     // f16 [16384][256]
#define O_GIH1  50331648UL     // f16 [16384][1024]
#define O_DECT  33554432UL     // tagged decp: [512][4096] x 8B {f16 h0, f16 h1, u32 tag} = 16MB exactly
#define O_WQV   92274688UL     // f16 [512][256]; dead after gemm1 -> tagged cpub/h2pub
#define O_CPUBT 92274688UL     // tagged cpub:  [2][4096] x 8B = 64KB
#define O_H2PT  92340224UL     // tagged h2pub: [2][4096] x 8B = 64KB
#define O_W1    92536832UL     // f16 [1024][512]
#define O_W2    93585408UL     // f16 [1024][512]
#define O_WHH1  94633984UL     // f16 [1024][256]
#define O_WHH2  95158272UL     // f16 [1024][256]
#define O_BQV   95682560UL     // f32 [512]
#define O_B1    95684608UL     // f32 [1024]
#define O_B2    95688704UL     // f32 [1024]
#define O_V2    95692800UL     // f32 [256]  (= -2*V)
#define O_SUMV  95693824UL     // f32 [1]
#define WS_NEED 95776768UL

__device__ __forceinline__ float fast_sigmoid(float x){
  float e = __builtin_amdgcn_exp2f(-L2E * x);
  return __builtin_amdgcn_rcpf(1.f + e);
}
__device__ __forceinline__ float fast_tanh(float x){
  float e = __builtin_amdgcn_exp2f(K2E * x);
  return 1.f - 2.f * __builtin_amdgcn_rcpf(1.f + e);
}

// ---- tagged-publish protocol helpers ----
// Producer: ONE 8B agent-scope store carrying {f16 v0, f16 v1, u32 tag}.
__device__ __forceinline__ void store_tag(void* p, float a, float b, unsigned tag){
  union { unsigned long long u; unsigned w[2]; } v;
  union { unsigned u; f16 h[2]; } d;
  d.h[0] = (f16)a; d.h[1] = (f16)b;
  v.w[0] = d.u; v.w[1] = tag;
  __hip_atomic_store((unsigned long long*)p, v.u, __ATOMIC_RELAXED, __HIP_MEMORY_SCOPE_AGENT);
}
// Consumer: cache-bypassing 16B load of two tagged units {d0,t0,d1,t1}.
template<int OFF>
__device__ __forceinline__ int4 ld_i4(const char* p){
  int4 r;
  asm volatile("global_load_dwordx4 %0, %1, off offset:%c2 sc0 sc1"
               : "=v"(r) : "v"(p), "i"(OFF) : "memory");
  return r;
}
__device__ __forceinline__ f16x8 mk_frag(int4 r0, int4 r1){
  union { f16x8 f; int i[4]; } u;
  u.i[0] = r0.x; u.i[1] = r0.z; u.i[2] = r1.x; u.i[3] = r1.z;
  return u.f;
}

// ============ prep: weight conversions, biases =========
__global__ __launch_bounds__(256) void prep_kernel(
    const float* __restrict__ attn_W, const float* __restrict__ attn_b, const float* __restrict__ attn_V,
    const float* __restrict__ l1_Wih, const float* __restrict__ l1_Whh,
    const float* __restrict__ l1_bih, const float* __restrict__ l1_bhh,
    const float* __restrict__ l2_Wih, const float* __restrict__ l2_Whh,
    const float* __restrict__ l2_bih, const float* __restrict__ l2_bhh,
    const float* __restrict__ bcs, char* __restrict__ ws)
{
  long gid = (long)blockIdx.x*256 + threadIdx.x;
  if (gid < 131072){
    int j = (int)(gid >> 8), k = (int)(gid & 255);
    float v = (j < 256) ? attn_W[j*512 + k] : attn_W[(j-256)*512 + 256 + k];
    ((f16*)(ws+O_WQV))[gid] = (f16)(K2E * v);
    return;
  }
  gid -= 131072;
  if (gid < 524288){ ((f16*)(ws+O_W1))[gid] = (f16)l1_Wih[gid]; return; }
  gid -= 524288;
  if (gid < 524288){ ((f16*)(ws+O_W2))[gid] = (f16)l2_Wih[gid]; return; }
  gid -= 524288;
  if (gid < 262144){ ((f16*)(ws+O_WHH1))[gid] = (f16)l1_Whh[gid]; return; }
  gid -= 262144;
  if (gid < 262144){ ((f16*)(ws+O_WHH2))[gid] = (f16)l2_Whh[gid]; return; }
  gid -= 262144;
  if (gid < 512){ ((float*)(ws+O_BQV))[gid] = (gid < 256) ? 0.f : K2E*attn_b[gid-256]; return; }
  gid -= 512;
  if (gid < 1024){ ((float*)(ws+O_B1))[gid] = l1_bih[gid] + l1_bhh[gid]; return; }
  gid -= 1024;
  if (gid < 1024){ ((float*)(ws+O_B2))[gid] = l2_bih[gid] + l2_bhh[gid]; return; }
  gid -= 1024;
  if (gid < 256){ ((float*)(ws+O_V2))[gid] = -2.f*attn_V[gid]; return; }
  gid -= 256;
  if (gid == 0){
    float s = 0.f;
    for (int h=0; h<256; h++) s += attn_V[h];
    *((float*)(ws+O_SUMV)) = s;
  }
}

// ============ enc f32 -> f16 ============
__global__ __launch_bounds__(256) void encf_kernel(const float* __restrict__ enc, char* __restrict__ ws){
  f16* dst = (f16*)(ws + O_ENCF);
  int i = (blockIdx.x*256 + threadIdx.x)*4;
  float4 v = *(const float4*)(enc + i);
  f16x4 o; o[0] = (f16)v.x; o[1] = (f16)v.y; o[2] = (f16)v.z; o[3] = (f16)v.w;
  *(f16x4*)(dst + i) = o;
}

// ============ NT GEMM: C[M,N](f32|f16) = A[M,256(+256)] * B[N,K]^T + bias =========
template<bool CF16>
__global__ __launch_bounds__(256) void gemm_nt(const f16* __restrict__ A0, const f16* __restrict__ A1,
     int K0, const f16* __restrict__ B, int ldb, void* __restrict__ Cp, int ldc,
     int K, const float* __restrict__ bias)
{
  __shared__ f16 As[4096];
  __shared__ f16 Bs[4096];
  const int tid = threadIdx.x;
  const int lane = tid & 63;
  const int wave = tid >> 6;
  const int lm = lane & 15, kg = lane >> 4;
  const int mbase = blockIdx.y * 128;
  const int nbase = blockIdx.x * 128;
  const int wm = (wave >> 1) * 64, wn = (wave & 1) * 64;
  f32x4 acc[4][4];
#pragma unroll
  for (int i=0;i<4;i++)
#pragma unroll
    for (int j=0;j<4;j++) acc[i][j] = 0;
  const int r = tid >> 1, seg = tid & 1;
  for (int kc=0; kc<K; kc+=32){
    const f16* Ap = A0; int kk = kc;
    if (A1 && kc >= K0){ Ap = A1; kk = kc - K0; }
    {
      const f16* srcA = Ap + (size_t)(mbase + r)*256 + kk + seg*16;
      f16x8 va0 = *(const f16x8*)(srcA);
      f16x8 va1 = *(const f16x8*)(srcA + 8);
      *(f16x8*)&As[((seg*2+0)*128 + r)*8] = va0;
      *(f16x8*)&As[((seg*2+1)*128 + r)*8] = va1;
      const f16* srcB = B + (size_t)(nbase + r)*ldb + kc + seg*16;
      f16x8 vb0 = *(const f16x8*)(srcB);
      f16x8 vb1 = *(const f16x8*)(srcB + 8);
      *(f16x8*)&Bs[((seg*2+0)*128 + r)*8] = vb0;
      *(f16x8*)&Bs[((seg*2+1)*128 + r)*8] = vb1;
    }
    __syncthreads();
    f16x8 af[4], bfr[4];
#pragma unroll
    for (int i=0;i<4;i++) af[i]  = *(const f16x8*)&As[(kg*128 + wm + i*16 + lm)*8];
#pragma unroll
    for (int j=0;j<4;j++) bfr[j] = *(const f16x8*)&Bs[(kg*128 + wn + j*16 + lm)*8];
#pragma unroll
    for (int i=0;i<4;i++)
#pragma unroll
      for (int j=0;j<4;j++)
        acc[i][j] = __builtin_amdgcn_mfma_f32_16x16x32_f16(af[i], bfr[j], acc[i][j], 0,0,0);
    __syncthreads();
  }
#pragma unroll
  for (int i=0;i<4;i++){
#pragma unroll
    for (int j=0;j<4;j++){
      int col = nbase + wn + j*16 + lm;
      float bv = bias ? bias[col] : 0.f;
#pragma unroll
      for (int rr=0;rr<4;rr++){
        int row = mbase + wm + i*16 + kg*4 + rr;
        float v = acc[i][j][rr] + bv;
        if (CF16) ((f16*)Cp)[(size_t)row*ldc + col] = (f16)v;
        else      ((float*)Cp)[(size_t)row*ldc + col] = v;
      }
    }
  }
}

// ============ fused attention scores + softmax + ctx ============
__global__ __launch_bounds__(256) void score_ctx_kernel(char* __restrict__ ws,
     const float* __restrict__ enc, const int* __restrict__ inp_len)
{
  __shared__ float s_pq[8][260];
  __shared__ float s_pv[32][260];
  __shared__ float s_sc[8][512];
  __shared__ float s_v2[256];
  __shared__ float s_sv[1];
  const int tid = threadIdx.x;
  const int b = blockIdx.y;
  const int t0 = blockIdx.x * 8;
  const float* pqv = (const float*)(ws + O_PQV);
  f16* ctx = (f16*)(ws + O_CTX);
  const int len = inp_len[b];
  {
    int row = tid >> 5, cb = (tid & 31) * 8;
    const float* src = pqv + (size_t)(b*512 + t0 + row)*512 + cb;
    *(float4*)&s_pq[row][cb]   = *(const float4*)(src);
    *(float4*)&s_pq[row][cb+4] = *(const float4*)(src+4);
    s_v2[tid] = ((const float*)(ws + O_V2))[tid];
    if (tid == 0) s_sv[0] = *((const float*)(ws + O_SUMV));
  }
  const int tt = tid >> 5;
  const int ss2 = tid & 31;
  for (int st=0; st<16; st++){
    {
      int row = tid >> 3, cb = (tid & 7) * 32;
      const float* src = pqv + (size_t)(b*512 + st*32 + row)*512 + 256 + cb;
#pragma unroll
      for (int c=0;c<32;c+=4) *(float4*)&s_pv[row][cb+c] = *(const float4*)(src+c);
    }
    __syncthreads();
    float a0=0.f,a1=0.f,a2=0.f,a3=0.f;
#pragma unroll 8
    for (int h=0;h<256;h+=4){
      float4 q = *(const float4*)&s_pq[tt][h];
      float4 p = *(const float4*)&s_pv[ss2][h];
      float4 w = *(const float4*)&s_v2[h];
      float e0 = __builtin_amdgcn_exp2f(q.x+p.x);
      float e1 = __builtin_amdgcn_exp2f(q.y+p.y);
      float e2 = __builtin_amdgcn_exp2f(q.z+p.z);
      float e3 = __builtin_amdgcn_exp2f(q.w+p.w);
      a0 += w.x * __builtin_amdgcn_rcpf(1.f+e0);
      a1 += w.y * __builtin_amdgcn_rcpf(1.f+e1);
      a2 += w.z * __builtin_amdgcn_rcpf(1.f+e2);
      a3 += w.w * __builtin_amdgcn_rcpf(1.f+e3);
    }
    int s = st*32 + ss2;
    float sc = s_sv[0] + ((a0+a1)+(a2+a3));
    if (s >= len) sc = -1.0e9f;
    s_sc[tt][s] = sc;
    __syncthreads();
  }
  {
    float m = -3.0e38f;
#pragma unroll
    for (int k2=0;k2<16;k2++) m = fmaxf(m, s_sc[tt][ss2 + 32*k2]);
#pragma unroll
    for (int off=16; off>=1; off>>=1) m = fmaxf(m, __shfl_xor(m, off, 64));
    float sum = 0.f;
    float ebuf[16];
#pragma unroll
    for (int k2=0;k2<16;k2++){
      float e = __builtin_amdgcn_exp2f((s_sc[tt][ss2+32*k2] - m) * L2E);
      ebuf[k2] = e; sum += e;
    }
#pragma unroll
    for (int off=16; off>=1; off>>=1) sum += __shfl_xor(sum, off, 64);
    float rinv = __builtin_amdgcn_rcpf(sum);
#pragma unroll
    for (int k2=0;k2<16;k2++) s_sc[tt][ss2+32*k2] = ebuf[k2]*rinv;
  }
  __syncthreads();
  float acc[8] = {0,0,0,0,0,0,0,0};
  const int hg = tid & 31;
  for (int st=0; st<16; st++){
    {
      int row = tid >> 3, cb = (tid & 7)*32;
      const float* src = enc + (size_t)(b*512 + st*32 + row)*256 + cb;
#pragma unroll
      for (int c=0;c<32;c+=4) *(float4*)&s_pv[row][cb+c] = *(const float4*)(src+c);
    }
    __syncthreads();
#pragma unroll 4
    for (int si=0; si<32; si++){
      float a = s_sc[tt][st*32+si];
#pragma unroll
      for (int u=0;u<8;u++) acc[u] += a * s_pv[si][hg + 32*u];
    }
    __syncthreads();
  }
#pragma unroll
  for (int u=0;u<8;u++)
    ctx[(size_t)(b*512 + t0 + tt)*256 + hg + 32*u] = (f16)acc[u];
}

// ============ recurrences: 16 blocks layer-1 + 16 blocks layer-2 ============
// R5 structure (tagged data + split gather via LDS). L2 change vs R5: the 8 h2
// loads are ISSUED at loop-top (fire-and-forget), the dec poll + x-MFMAs run
// while they fly, and only the residual h2 wait is exposed. (R8's mistake --
// issuing h2 loads AFTER the x-phase -- is the opposite of this.)
__global__ __launch_bounds__(256) void rec_kernel(char* __restrict__ ws,
        const float* __restrict__ bhs, const float* __restrict__ bcs,
        const int* __restrict__ inp_len, float* __restrict__ out)
{
  __shared__ float s_g[4][32][17];
  __shared__ f16x8 s_buf[2048];   // L1: s_c=[0,1024). L2: s_x=[0,1024), s_h=[1024,2048)
  const int tid = threadIdx.x;
  const int lane = tid & 63;
  const int wave = tid >> 6;
  const int lm = lane & 15;
  const int kg = lane >> 4;
  char* cpubt = ws + O_CPUBT;   // [2][4096] x 8B
  char* h2pt  = ws + O_H2PT;    // [2][4096] x 8B
  char* decpt = ws + O_DECT;    // [512][4096] x 8B
  // gate-phase mapping: one batch, two adjacent k-components per thread
  const int b  = tid >> 3;
  const int kp = tid & 7;
  const int kl0 = kp*2, kl1 = kp*2 + 1;
  // this thread's gather slot (slot = 4 tagged units = 32B): quarter per wave
  const int gslot = wave*256 + lane;   // +{0,64,128,192} for q=0..3
  const int fs = kg*32 + lm;           // fragment slot base within a kc-chunk

  if (blockIdx.x < 16) {
    // ---- layer 1 (reference quirk: matmul uses carry c; c_new = f*h_prev + i*g~)
    const int isl = blockIdx.x;
    const f16* whh1 = (const f16*)(ws + O_WHH1);
    const f16* gih1 = (const f16*)(ws + O_GIH1);
    f16x8 bf[8];
    {
      int j = wave*256 + isl*16 + lm;
#pragma unroll
      for (int kc=0;kc<8;kc++) bf[kc] = *(const f16x8*)(whh1 + j*256 + kc*32 + kg*8);
    }
    float h0 = bhs[b*256 + isl*16 + kl0];
    float h1 = bhs[b*256 + isl*16 + kl1];
    const int kk0 = isl*16 + kl0;
    const int pu = ((kk0>>5)*128 + ((kk0>>3)&3)*32 + b)*32 + ((kk0&7)>>1)*8;
    // init: publish c(-1)=bcs slice with tag 1 into buffer 1
    store_tag(cpubt + 32768 + pu, bcs[b*256 + kk0], bcs[b*256 + kk0 + 1], 1u);
    for (int t=0;t<512;t++){
      // prefetch gih (plain cached loads, address depends only on t)
      const f16* gp = gih1 + (size_t)(b*512 + t)*1024 + isl*16 + kl0;
      f16x2 gv0 = *(const f16x2*)(gp);
      f16x2 gv1 = *(const f16x2*)(gp+256);
      f16x2 gv2 = *(const f16x2*)(gp+512);
      f16x2 gv3 = *(const f16x2*)(gp+768);
      // split tagged poll of cpub[(t+1)&1]: this wave's quarter only
      const char* cb = cpubt + (((t+1)&1)<<15);
      const char* pk0 = cb + (size_t)gslot*32;
      const char* pk2 = pk0 + 4096;
      const unsigned want = (unsigned)(t+1);
      int4 r[8];
      while (true){
        r[0] = ld_i4<0>(pk0);    r[1] = ld_i4<16>(pk0);
        r[2] = ld_i4<2048>(pk0); r[3] = ld_i4<2064>(pk0);
        r[4] = ld_i4<0>(pk2);    r[5] = ld_i4<16>(pk2);
        r[6] = ld_i4<2048>(pk2); r[7] = ld_i4<2064>(pk2);
        asm volatile("s_waitcnt vmcnt(0)" ::: "memory");
        __builtin_amdgcn_sched_barrier(0);
        unsigned mn = 0xFFFFFFFFu;
#pragma unroll
        for (int i=0;i<8;i++){
          unsigned t0 = (unsigned)r[i].y, t1 = (unsigned)r[i].w;
          mn = mn < t0 ? mn : t0;
          mn = mn < t1 ? mn : t1;
        }
        if (__all((int)(mn >= want))) break;
      }
      // strip tags, publish quarter to LDS
      s_buf[gslot]       = mk_frag(r[0], r[1]);
      s_buf[gslot + 64]  = mk_frag(r[2], r[3]);
      s_buf[gslot + 128] = mk_frag(r[4], r[5]);
      s_buf[gslot + 192] = mk_frag(r[6], r[7]);
      __syncthreads();
      f32x4 acc0 = 0, acc1 = 0;
#pragma unroll
      for (int kc=0;kc<8;kc++){
        f16x8 a0 = s_buf[kc*128 + fs];
        f16x8 a1 = s_buf[kc*128 + fs + 16];
        acc0 = __builtin_amdgcn_mfma_f32_16x16x32_f16(a0, bf[kc], acc0, 0,0,0);
        acc1 = __builtin_amdgcn_mfma_f32_16x16x32_f16(a1, bf[kc], acc1, 0,0,0);
      }
#pragma unroll
      for (int rr=0;rr<4;rr++){
        s_g[wave][kg*4+rr][lm] = acc0[rr];
        s_g[wave][16+kg*4+rr][lm] = acc1[rr];
      }
      __syncthreads();
      {
        float gi0 = s_g[0][b][kl0] + (float)gv0[0];
        float gi1 = s_g[0][b][kl1] + (float)gv0[1];
        float gf0 = s_g[1][b][kl0] + (float)gv1[0];
        float gf1 = s_g[1][b][kl1] + (float)gv1[1];
        float gc0 = s_g[2][b][kl0] + (float)gv2[0];
        float gc1 = s_g[2][b][kl1] + (float)gv2[1];
        float go0 = s_g[3][b][kl0] + (float)gv3[0];
        float go1 = s_g[3][b][kl1] + (float)gv3[1];
        float cn0 = fast_sigmoid(gf0)*h0 + fast_sigmoid(gi0)*fast_tanh(gc0);  // quirk
        float cn1 = fast_sigmoid(gf1)*h1 + fast_sigmoid(gi1)*fast_tanh(gc1);
        float hn0 = fast_sigmoid(go0)*fast_tanh(cn0);
        float hn1 = fast_sigmoid(go1)*fast_tanh(cn1);
        h0 = hn0; h1 = hn1;
        store_tag(cpubt + ((t&1)<<15) + pu, cn0, cn1, (unsigned)(t+2));
        store_tag(decpt + ((size_t)t<<15) + pu, hn0, hn1, (unsigned)(t+2));
      }
      // no drain, no flag: tags travel with the data
    }
  } else {
    // ---- layer 2 (standard cell, masked freeze)
    const int isl = blockIdx.x - 16;
    const f16* whh2 = (const f16*)(ws + O_WHH2);
    const f16* w2   = (const f16*)(ws + O_W2);
    const f16* gih2 = (const f16*)(ws + O_GIH2C);
    f16x8 bfh[8], bfx[8];
    {
      int j = wave*256 + isl*16 + lm;
#pragma unroll
      for (int kc=0;kc<8;kc++){
        bfh[kc] = *(const f16x8*)(whh2 + j*256 + kc*32 + kg*8);
        bfx[kc] = *(const f16x8*)(w2 + j*512 + kc*32 + kg*8);
      }
    }
    float c0 = 0.f, c1 = 0.f, hh0 = 0.f, hh1 = 0.f;
    const int lenv = inp_len[b];
    const int kk0 = isl*16 + kl0;
    const int pu = ((kk0>>5)*128 + ((kk0>>3)&3)*32 + b)*32 + ((kk0&7)>>1)*8;
    // init: publish h2(-1)=0 with tag 1 into buffer 1
    store_tag(h2pt + 32768 + pu, 0.f, 0.f, 1u);
    for (int t=0;t<512;t++){
      // ---- issue the 8 h2 loads FIRST (fire-and-forget). h2(t-1)'s RTT clock
      // started at our store last step; these values land during dec-poll + x.
      const char* hb = h2pt + (((t+1)&1)<<15);
      const char* ph0 = hb + (size_t)gslot*32;
      const char* ph2 = ph0 + 4096;
      int4 rh[8];
      rh[0] = ld_i4<0>(ph0);    rh[1] = ld_i4<16>(ph0);
      rh[2] = ld_i4<2048>(ph0); rh[3] = ld_i4<2064>(ph0);
      rh[4] = ld_i4<0>(ph2);    rh[5] = ld_i4<16>(ph2);
      rh[6] = ld_i4<2048>(ph2); rh[7] = ld_i4<2064>(ph2);
      const f16* gp = gih2 + (size_t)(b*512 + t)*1024 + isl*16 + kl0;
      f16x2 gv0 = *(const f16x2*)(gp);
      f16x2 gv1 = *(const f16x2*)(gp+256);
      f16x2 gv2 = *(const f16x2*)(gp+512);
      f16x2 gv3 = *(const f16x2*)(gp+768);
      f32x4 acc0 = 0, acc1 = 0;
      // ---- dec poll (want t+2); its vmcnt(0) also drains the early rh loads
      {
        const char* xb = decpt + ((size_t)t<<15);
        const char* px0 = xb + (size_t)gslot*32;
        const char* px2 = px0 + 4096;
        const unsigned wantx = (unsigned)(t+2);
        int4 rx[8];
        while (true){
          rx[0] = ld_i4<0>(px0);    rx[1] = ld_i4<16>(px0);
          rx[2] = ld_i4<2048>(px0); rx[3] = ld_i4<2064>(px0);
          rx[4] = ld_i4<0>(px2);    rx[5] = ld_i4<16>(px2);
          rx[6] = ld_i4<2048>(px2); rx[7] = ld_i4<2064>(px2);
          asm volatile("s_waitcnt vmcnt(0)" ::: "memory");
          __builtin_amdgcn_sched_barrier(0);
          unsigned mn = 0xFFFFFFFFu;
#pragma unroll
          for (int i=0;i<8;i++){
            unsigned a0 = (unsigned)rx[i].y, a1 = (unsigned)rx[i].w;
            mn = mn < a0 ? mn : a0;
            mn = mn < a1 ? mn : a1;
          }
          if (__all((int)(mn >= wantx))) break;
        }
        s_buf[gslot]       = mk_frag(rx[0], rx[1]);
        s_buf[gslot + 64]  = mk_frag(rx[2], rx[3]);
        s_buf[gslot + 128] = mk_frag(rx[4], rx[5]);
        s_buf[gslot + 192] = mk_frag(rx[6], rx[7]);
      }
      __syncthreads();
      // ---- x-MFMAs run while the h2 values (already fetched) age toward validity
#pragma unroll
      for (int kc=0;kc<8;kc++){
        f16x8 ax0 = s_buf[kc*128 + fs];
        f16x8 ax1 = s_buf[kc*128 + fs + 16];
        acc0 = __builtin_amdgcn_mfma_f32_16x16x32_f16(ax0, bfx[kc], acc0, 0,0,0);
        acc1 = __builtin_amdgcn_mfma_f32_16x16x32_f16(ax1, bfx[kc], acc1, 0,0,0);
      }
      // ---- h2 tag check on the early-fetched values; spin only on residual
      {
        const unsigned wanth = (unsigned)(t+1);
        unsigned mn = 0xFFFFFFFFu;
#pragma unroll
        for (int i=0;i<8;i++){
          unsigned b0 = (unsigned)rh[i].y, b1 = (unsigned)rh[i].w;
          mn = mn < b0 ? mn : b0;
          mn = mn < b1 ? mn : b1;
        }
        while (!__all((int)(mn >= wanth))){
          rh[0] = ld_i4<0>(ph0);    rh[1] = ld_i4<16>(ph0);
          rh[2] = ld_i4<2048>(ph0); rh[3] = ld_i4<2064>(ph0);
          rh[4] = ld_i4<0>(ph2);    rh[5] = ld_i4<16>(ph2);
          rh[6] = ld_i4<2048>(ph2); rh[7] = ld_i4<2064>(ph2);
          asm volatile("s_waitcnt vmcnt(0)" ::: "memory");
          __builtin_amdgcn_sched_barrier(0);
          mn = 0xFFFFFFFFu;
#pragma unroll
          for (int i=0;i<8;i++){
            unsigned b0 = (unsigned)rh[i].y, b1 = (unsigned)rh[i].w;
            mn = mn < b0 ? mn : b0;
            mn = mn < b1 ? mn : b1;
          }
        }
        // publish h2 quarter ([1024,2048) -- disjoint from x reads of [0,1024))
        s_buf[1024 + gslot]       = mk_frag(rh[0], rh[1]);
        s_buf[1024 + gslot + 64]  = mk_frag(rh[2], rh[3]);
        s_buf[1024 + gslot + 128] = mk_frag(rh[4], rh[5]);
        s_buf[1024 + gslot + 192] = mk_frag(rh[6], rh[7]);
      }
      __syncthreads();
#pragma unroll
      for (int kc=0;kc<8;kc++){
        f16x8 ah0 = s_buf[1024 + kc*128 + fs];
        f16x8 ah1 = s_buf[1024 + kc*128 + fs + 16];
        acc0 = __builtin_amdgcn_mfma_f32_16x16x32_f16(ah0, bfh[kc], acc0, 0,0,0);
        acc1 = __builtin_amdgcn_mfma_f32_16x16x32_f16(ah1, bfh[kc], acc1, 0,0,0);
      }
#pragma unroll
      for (int rr=0;rr<4;rr++){
        s_g[wave][kg*4+rr][lm] = acc0[rr];
        s_g[wave][16+kg*4+rr][lm] = acc1[rr];
      }
      __syncthreads();
      float ov0, ov1;
      {
        float gi0 = s_g[0][b][kl0] + (float)gv0[0];
        float gi1 = s_g[0][b][kl1] + (float)gv0[1];
        float gf0 = s_g[1][b][kl0] + (float)gv1[0];
        float gf1 = s_g[1][b][kl1] + (float)gv1[1];
        float gc0 = s_g[2][b][kl0] + (float)gv2[0];
        float gc1 = s_g[2][b][kl1] + (float)gv2[1];
        float go0 = s_g[3][b][kl0] + (float)gv3[0];
        float go1 = s_g[3][b][kl1] + (float)gv3[1];
        float cn0 = fast_sigmoid(gf0)*c0 + fast_sigmoid(gi0)*fast_tanh(gc0);
        float cn1 = fast_sigmoid(gf1)*c1 + fast_sigmoid(gi1)*fast_tanh(gc1);
        float hn0 = fast_sigmoid(go0)*fast_tanh(cn0);
        float hn1 = fast_sigmoid(go1)*fast_tanh(cn1);
        bool valid = (t < lenv);
        c0 = valid ? cn0 : c0;
        c1 = valid ? cn1 : c1;
        hh0 = valid ? hn0 : hh0;
        hh1 = valid ? hn1 : hh1;
        ov0 = valid ? hn0 : 0.f;
        ov1 = valid ? hn1 : 0.f;
        store_tag(h2pt + ((t&1)<<15) + pu, hh0, hh1, (unsigned)(t+2));
      }
      float2 ov; ov.x = ov0; ov.y = ov1;
      *(float2*)(out + (size_t)(b*512 + t)*256 + isl*16 + kl0) = ov;
    }
  }
}

extern "C" void kernel_launch(void* const* d_in, const int* in_sizes, int n_in,
                              void* d_out, int out_size, void* d_ws, size_t ws_size,
                              hipStream_t stream) {
  if (ws_size < WS_NEED) return;  // workspace too small; bail (output stays poison -> visible failure)
  const float* enc    = (const float*)d_in[0];
  const float* bhs    = (const float*)d_in[1];
  const float* bcs    = (const float*)d_in[2];
  const float* attn_W = (const float*)d_in[3];
  const float* attn_b = (const float*)d_in[4];
  const float* attn_V = (const float*)d_in[5];
  const float* l1_Wih = (const float*)d_in[6];
  const float* l1_Whh = (const float*)d_in[7];
  const float* l1_bih = (const float*)d_in[8];
  const float* l1_bhh = (const float*)d_in[9];
  const float* l2_Wih = (const float*)d_in[10];
  const float* l2_Whh = (const float*)d_in[11];
  const float* l2_bih = (const float*)d_in[12];
  const float* l2_bhh = (const float*)d_in[13];
  const int* inp_len  = (const int*)d_in[14];
  char* ws = (char*)d_ws;
  float* out = (float*)d_out;

  prep_kernel<<<6700, 256, 0, stream>>>(attn_W, attn_b, attn_V, l1_Wih, l1_Whh, l1_bih, l1_bhh,
                                        l2_Wih, l2_Whh, l2_bih, l2_bhh, bcs, ws);
  encf_kernel<<<4096, 256, 0, stream>>>(enc, ws);
  // pqv = k2*(enc@Wq^T | enc@Wv^T + b)
  gemm_nt<false><<<dim3(4,128), 256, 0, stream>>>((const f16*)(ws+O_ENCF), nullptr, 256,
        (const f16*)(ws+O_WQV), 256, (void*)(ws+O_PQV), 512, 256, (const float*)(ws+O_BQV));
  score_ctx_kernel<<<dim3(64,32), 256, 0, stream>>>(ws, enc, inp_len);
  // gih1 = [enc|ctx]@W1^T + (bih1+bhh1)
  gemm_nt<true><<<dim3(8,128), 256, 0, stream>>>((const f16*)(ws+O_ENCF), (const f16*)(ws+O_CTX), 256,
        (const f16*)(ws+O_W1), 512, (void*)(ws+O_GIH1), 1024, 512, (const float*)(ws+O_B1));
  // gih2c = ctx@W2R^T + (bih2+bhh2)   (aliases pqv region; pqv dead after score_ctx)
  gemm_nt<true><<<dim3(8,128), 256, 0, stream>>>((const f16*)(ws+O_CTX), nullptr, 256,
        (const f16*)(ws+O_W2)+256, 512, (void*)(ws+O_GIH2C), 1024, 256, (const float*)(ws+O_B2));
  // zero tag regions (CTX/ENCF and WQV are dead after the gemms above)
  hipMemsetAsync(ws + O_DECT, 0, 16777216UL, stream);
  hipMemsetAsync(ws + O_CPUBT, 0, 131072UL, stream);
  rec_kernel<<<32, 256, 0, stream>>>(ws, bhs, bcs, inp_len, out);
}

// Round 10
// 1917.559 us; speedup vs baseline: 1.3468x; 1.3468x over previous
//
#include <hip/hip_runtime.h>

typedef _Float16 f16;
typedef _Float16 f16x2 __attribute__((ext_vector_type(2)));
typedef _Float16 f16x8 __attribute__((ext_vector_type(8)));
typedef _Float16 f16x4 __attribute__((ext_vector_type(4)));
typedef float f32x4 __attribute__((ext_vector_type(4)));

#define L2E 1.4426950408889634f
#define K2E 2.8853900817779268f

// ---- workspace layout (bytes)
#define O_PQV   0UL            // f32 [16384][512]  (aliased by GIH2C later)
#define O_GIH2C 0UL            // f16 [16384][1024]
#define O_CTX   33554432UL     // f16 [16384][256]; after last gemm -> tagged decp (16MB, spans CTX+ENCF)
#define O_ENCF  41943040UL     // f16 [16384][256]
#define O_GIH1  50331648UL     // f16 [16384][1024]
#define O_DECT  33554432UL     // tagged decp: [512][4096] x 8B {f16 h0, f16 h1, u32 tag} = 16MB exactly
#define O_WQV   92274688UL     // f16 [512][256]; dead after gemm1 -> tagged cpub/h2pub
#define O_CPUBT 92274688UL     // tagged cpub:  [2][4096] x 8B = 64KB
#define O_H2PT  92340224UL     // tagged h2pub: [2][4096] x 8B = 64KB
#define O_W1    92536832UL     // f16 [1024][512]
#define O_W2    93585408UL     // f16 [1024][512]
#define O_WHH1  94633984UL     // f16 [1024][256]
#define O_WHH2  95158272UL     // f16 [1024][256]
#define O_BQV   95682560UL     // f32 [512]
#define O_B1    95684608UL     // f32 [1024]
#define O_B2    95688704UL     // f32 [1024]
#define O_V2    95692800UL     // f32 [256]  (= -2*V)
#define O_SUMV  95693824UL     // f32 [1]
#define WS_NEED 95776768UL

__device__ __forceinline__ float fast_sigmoid(float x){
  float e = __builtin_amdgcn_exp2f(-L2E * x);
  return __builtin_amdgcn_rcpf(1.f + e);
}
__device__ __forceinline__ float fast_tanh(float x){
  float e = __builtin_amdgcn_exp2f(K2E * x);
  return 1.f - 2.f * __builtin_amdgcn_rcpf(1.f + e);
}

// ---- tagged-publish protocol helpers ----
// Producer: ONE 8B agent-scope store carrying {f16 v0, f16 v1, u32 tag}.
__device__ __forceinline__ void store_tag(void* p, float a, float b, unsigned tag){
  union { unsigned long long u; unsigned w[2]; } v;
  union { unsigned u; f16 h[2]; } d;
  d.h[0] = (f16)a; d.h[1] = (f16)b;
  v.w[0] = d.u; v.w[1] = tag;
  __hip_atomic_store((unsigned long long*)p, v.u, __ATOMIC_RELAXED, __HIP_MEMORY_SCOPE_AGENT);
}
// Consumer: cache-bypassing 16B load of two tagged units {d0,t0,d1,t1}.
template<int OFF>
__device__ __forceinline__ int4 ld_i4(const char* p){
  int4 r;
  asm volatile("global_load_dwordx4 %0, %1, off offset:%c2 sc0 sc1"
               : "=v"(r) : "v"(p), "i"(OFF) : "memory");
  return r;
}
__device__ __forceinline__ f16x8 mk_frag(int4 r0, int4 r1){
  union { f16x8 f; int i[4]; } u;
  u.i[0] = r0.x; u.i[1] = r0.z; u.i[2] = r1.x; u.i[3] = r1.z;
  return u.f;
}

// ============ prep: weight conversions, biases =========
__global__ __launch_bounds__(256) void prep_kernel(
    const float* __restrict__ attn_W, const float* __restrict__ attn_b, const float* __restrict__ attn_V,
    const float* __restrict__ l1_Wih, const float* __restrict__ l1_Whh,
    const float* __restrict__ l1_bih, const float* __restrict__ l1_bhh,
    const float* __restrict__ l2_Wih, const float* __restrict__ l2_Whh,
    const float* __restrict__ l2_bih, const float* __restrict__ l2_bhh,
    const float* __restrict__ bcs, char* __restrict__ ws)
{
  long gid = (long)blockIdx.x*256 + threadIdx.x;
  if (gid < 131072){
    int j = (int)(gid >> 8), k = (int)(gid & 255);
    float v = (j < 256) ? attn_W[j*512 + k] : attn_W[(j-256)*512 + 256 + k];
    ((f16*)(ws+O_WQV))[gid] = (f16)(K2E * v);
    return;
  }
  gid -= 131072;
  if (gid < 524288){ ((f16*)(ws+O_W1))[gid] = (f16)l1_Wih[gid]; return; }
  gid -= 524288;
  if (gid < 524288){ ((f16*)(ws+O_W2))[gid] = (f16)l2_Wih[gid]; return; }
  gid -= 524288;
  if (gid < 262144){ ((f16*)(ws+O_WHH1))[gid] = (f16)l1_Whh[gid]; return; }
  gid -= 262144;
  if (gid < 262144){ ((f16*)(ws+O_WHH2))[gid] = (f16)l2_Whh[gid]; return; }
  gid -= 262144;
  if (gid < 512){ ((float*)(ws+O_BQV))[gid] = (gid < 256) ? 0.f : K2E*attn_b[gid-256]; return; }
  gid -= 512;
  if (gid < 1024){ ((float*)(ws+O_B1))[gid] = l1_bih[gid] + l1_bhh[gid]; return; }
  gid -= 1024;
  if (gid < 1024){ ((float*)(ws+O_B2))[gid] = l2_bih[gid] + l2_bhh[gid]; return; }
  gid -= 1024;
  if (gid < 256){ ((float*)(ws+O_V2))[gid] = -2.f*attn_V[gid]; return; }
  gid -= 256;
  if (gid == 0){
    float s = 0.f;
    for (int h=0; h<256; h++) s += attn_V[h];
    *((float*)(ws+O_SUMV)) = s;
  }
}

// ============ enc f32 -> f16 ============
__global__ __launch_bounds__(256) void encf_kernel(const float* __restrict__ enc, char* __restrict__ ws){
  f16* dst = (f16*)(ws + O_ENCF);
  int i = (blockIdx.x*256 + threadIdx.x)*4;
  float4 v = *(const float4*)(enc + i);
  f16x4 o; o[0] = (f16)v.x; o[1] = (f16)v.y; o[2] = (f16)v.z; o[3] = (f16)v.w;
  *(f16x4*)(dst + i) = o;
}

// ============ NT GEMM: C[M,N](f32|f16) = A[M,256(+256)] * B[N,K]^T + bias =========
template<bool CF16>
__global__ __launch_bounds__(256) void gemm_nt(const f16* __restrict__ A0, const f16* __restrict__ A1,
     int K0, const f16* __restrict__ B, int ldb, void* __restrict__ Cp, int ldc,
     int K, const float* __restrict__ bias)
{
  __shared__ f16 As[4096];
  __shared__ f16 Bs[4096];
  const int tid = threadIdx.x;
  const int lane = tid & 63;
  const int wave = tid >> 6;
  const int lm = lane & 15, kg = lane >> 4;
  const int mbase = blockIdx.y * 128;
  const int nbase = blockIdx.x * 128;
  const int wm = (wave >> 1) * 64, wn = (wave & 1) * 64;
  f32x4 acc[4][4];
#pragma unroll
  for (int i=0;i<4;i++)
#pragma unroll
    for (int j=0;j<4;j++) acc[i][j] = 0;
  const int r = tid >> 1, seg = tid & 1;
  for (int kc=0; kc<K; kc+=32){
    const f16* Ap = A0; int kk = kc;
    if (A1 && kc >= K0){ Ap = A1; kk = kc - K0; }
    {
      const f16* srcA = Ap + (size_t)(mbase + r)*256 + kk + seg*16;
      f16x8 va0 = *(const f16x8*)(srcA);
      f16x8 va1 = *(const f16x8*)(srcA + 8);
      *(f16x8*)&As[((seg*2+0)*128 + r)*8] = va0;
      *(f16x8*)&As[((seg*2+1)*128 + r)*8] = va1;
      const f16* srcB = B + (size_t)(nbase + r)*ldb + kc + seg*16;
      f16x8 vb0 = *(const f16x8*)(srcB);
      f16x8 vb1 = *(const f16x8*)(srcB + 8);
      *(f16x8*)&Bs[((seg*2+0)*128 + r)*8] = vb0;
      *(f16x8*)&Bs[((seg*2+1)*128 + r)*8] = vb1;
    }
    __syncthreads();
    f16x8 af[4], bfr[4];
#pragma unroll
    for (int i=0;i<4;i++) af[i]  = *(const f16x8*)&As[(kg*128 + wm + i*16 + lm)*8];
#pragma unroll
    for (int j=0;j<4;j++) bfr[j] = *(const f16x8*)&Bs[(kg*128 + wn + j*16 + lm)*8];
#pragma unroll
    for (int i=0;i<4;i++)
#pragma unroll
      for (int j=0;j<4;j++)
        acc[i][j] = __builtin_amdgcn_mfma_f32_16x16x32_f16(af[i], bfr[j], acc[i][j], 0,0,0);
    __syncthreads();
  }
#pragma unroll
  for (int i=0;i<4;i++){
#pragma unroll
    for (int j=0;j<4;j++){
      int col = nbase + wn + j*16 + lm;
      float bv = bias ? bias[col] : 0.f;
#pragma unroll
      for (int rr=0;rr<4;rr++){
        int row = mbase + wm + i*16 + kg*4 + rr;
        float v = acc[i][j][rr] + bv;
        if (CF16) ((f16*)Cp)[(size_t)row*ldc + col] = (f16)v;
        else      ((float*)Cp)[(size_t)row*ldc + col] = v;
      }
    }
  }
}

// ============ fused attention scores + softmax + ctx ============
// len-clipped: scores for s >= len are -1e9 -> softmax weight 0 -> all work on
// st-blocks with st*32 >= len is provably dead. stmax is block-uniform (len
// depends only on blockIdx.y), so the clipped loops keep barriers uniform.
__global__ __launch_bounds__(256) void score_ctx_kernel(char* __restrict__ ws,
     const float* __restrict__ enc, const int* __restrict__ inp_len)
{
  __shared__ float s_pq[8][260];
  __shared__ float s_pv[32][260];
  __shared__ float s_sc[8][512];
  __shared__ float s_v2[256];
  __shared__ float s_sv[1];
  const int tid = threadIdx.x;
  const int b = blockIdx.y;
  const int t0 = blockIdx.x * 8;
  const float* pqv = (const float*)(ws + O_PQV);
  f16* ctx = (f16*)(ws + O_CTX);
  const int len = inp_len[b];
  const int stmax = (len + 31) >> 5;   // >= 1 since len >= 1
  {
    int row = tid >> 5, cb = (tid & 31) * 8;
    const float* src = pqv + (size_t)(b*512 + t0 + row)*512 + cb;
    *(float4*)&s_pq[row][cb]   = *(const float4*)(src);
    *(float4*)&s_pq[row][cb+4] = *(const float4*)(src+4);
    s_v2[tid] = ((const float*)(ws + O_V2))[tid];
    if (tid == 0) s_sv[0] = *((const float*)(ws + O_SUMV));
  }
  const int tt = tid >> 5;
  const int ss2 = tid & 31;
  for (int st=0; st<stmax; st++){
    {
      int row = tid >> 3, cb = (tid & 7) * 32;
      const float* src = pqv + (size_t)(b*512 + st*32 + row)*512 + 256 + cb;
#pragma unroll
      for (int c=0;c<32;c+=4) *(float4*)&s_pv[row][cb+c] = *(const float4*)(src+c);
    }
    __syncthreads();
    float a0=0.f,a1=0.f,a2=0.f,a3=0.f;
#pragma unroll 8
    for (int h=0;h<256;h+=4){
      float4 q = *(const float4*)&s_pq[tt][h];
      float4 p = *(const float4*)&s_pv[ss2][h];
      float4 w = *(const float4*)&s_v2[h];
      float e0 = __builtin_amdgcn_exp2f(q.x+p.x);
      float e1 = __builtin_amdgcn_exp2f(q.y+p.y);
      float e2 = __builtin_amdgcn_exp2f(q.z+p.z);
      float e3 = __builtin_amdgcn_exp2f(q.w+p.w);
      a0 += w.x * __builtin_amdgcn_rcpf(1.f+e0);
      a1 += w.y * __builtin_amdgcn_rcpf(1.f+e1);
      a2 += w.z * __builtin_amdgcn_rcpf(1.f+e2);
      a3 += w.w * __builtin_amdgcn_rcpf(1.f+e3);
    }
    int s = st*32 + ss2;
    float sc = s_sv[0] + ((a0+a1)+(a2+a3));
    if (s >= len) sc = -1.0e9f;
    s_sc[tt][s] = sc;
    __syncthreads();
  }
  {
    float m = -3.0e38f;
    for (int k2=0;k2<stmax;k2++) m = fmaxf(m, s_sc[tt][ss2 + 32*k2]);
#pragma unroll
    for (int off=16; off>=1; off>>=1) m = fmaxf(m, __shfl_xor(m, off, 64));
    float sum = 0.f;
    float ebuf[16];
    for (int k2=0;k2<stmax;k2++){
      float e = __builtin_amdgcn_exp2f((s_sc[tt][ss2+32*k2] - m) * L2E);
      ebuf[k2] = e; sum += e;
    }
#pragma unroll
    for (int off=16; off>=1; off>>=1) sum += __shfl_xor(sum, off, 64);
    float rinv = __builtin_amdgcn_rcpf(sum);
    for (int k2=0;k2<stmax;k2++) s_sc[tt][ss2+32*k2] = ebuf[k2]*rinv;
  }
  __syncthreads();
  float acc[8] = {0,0,0,0,0,0,0,0};
  const int hg = tid & 31;
  for (int st=0; st<stmax; st++){
    {
      int row = tid >> 3, cb = (tid & 7)*32;
      const float* src = enc + (size_t)(b*512 + st*32 + row)*256 + cb;
#pragma unroll
      for (int c=0;c<32;c+=4) *(float4*)&s_pv[row][cb+c] = *(const float4*)(src+c);
    }
    __syncthreads();
#pragma unroll 4
    for (int si=0; si<32; si++){
      float a = s_sc[tt][st*32+si];
#pragma unroll
      for (int u=0;u<8;u++) acc[u] += a * s_pv[si][hg + 32*u];
    }
    __syncthreads();
  }
#pragma unroll
  for (int u=0;u<8;u++)
    ctx[(size_t)(b*512 + t0 + tt)*256 + hg + 32*u] = (f16)acc[u];
}

// ============ recurrences: 16 blocks layer-1 + 16 blocks layer-2 ============
// R5 structure, byte-exact revert (proven 1237 us): tagged data + split gather
// via LDS; L2 uses the merged 16-load single-vmcnt-window poll (R8/R9 proved
// any serialization of dec/h2 phases loses).
__global__ __launch_bounds__(256) void rec_kernel(char* __restrict__ ws,
        const float* __restrict__ bhs, const float* __restrict__ bcs,
        const int* __restrict__ inp_len, float* __restrict__ out)
{
  __shared__ float s_g[4][32][17];
  __shared__ f16x8 s_buf[2048];   // L1: s_c=[0,1024). L2: s_x=[0,1024), s_h=[1024,2048)
  const int tid = threadIdx.x;
  const int lane = tid & 63;
  const int wave = tid >> 6;
  const int lm = lane & 15;
  const int kg = lane >> 4;
  char* cpubt = ws + O_CPUBT;   // [2][4096] x 8B
  char* h2pt  = ws + O_H2PT;    // [2][4096] x 8B
  char* decpt = ws + O_DECT;    // [512][4096] x 8B
  // gate-phase mapping: one batch, two adjacent k-components per thread
  const int b  = tid >> 3;
  const int kp = tid & 7;
  const int kl0 = kp*2, kl1 = kp*2 + 1;
  // this thread's gather slot (slot = 4 tagged units = 32B): quarter per wave
  const int gslot = wave*256 + lane;   // +{0,64,128,192} for q=0..3
  const int fs = kg*32 + lm;           // fragment slot base within a kc-chunk

  if (blockIdx.x < 16) {
    // ---- layer 1 (reference quirk: matmul uses carry c; c_new = f*h_prev + i*g~)
    const int isl = blockIdx.x;
    const f16* whh1 = (const f16*)(ws + O_WHH1);
    const f16* gih1 = (const f16*)(ws + O_GIH1);
    f16x8 bf[8];
    {
      int j = wave*256 + isl*16 + lm;
#pragma unroll
      for (int kc=0;kc<8;kc++) bf[kc] = *(const f16x8*)(whh1 + j*256 + kc*32 + kg*8);
    }
    float h0 = bhs[b*256 + isl*16 + kl0];
    float h1 = bhs[b*256 + isl*16 + kl1];
    const int kk0 = isl*16 + kl0;
    const int pu = ((kk0>>5)*128 + ((kk0>>3)&3)*32 + b)*32 + ((kk0&7)>>1)*8;
    // init: publish c(-1)=bcs slice with tag 1 into buffer 1
    store_tag(cpubt + 32768 + pu, bcs[b*256 + kk0], bcs[b*256 + kk0 + 1], 1u);
    for (int t=0;t<512;t++){
      // prefetch gih (plain cached loads, address depends only on t)
      const f16* gp = gih1 + (size_t)(b*512 + t)*1024 + isl*16 + kl0;
      f16x2 gv0 = *(const f16x2*)(gp);
      f16x2 gv1 = *(const f16x2*)(gp+256);
      f16x2 gv2 = *(const f16x2*)(gp+512);
      f16x2 gv3 = *(const f16x2*)(gp+768);
      // split tagged poll of cpub[(t+1)&1]: this wave's quarter only
      const char* cb = cpubt + (((t+1)&1)<<15);
      const char* pk0 = cb + (size_t)gslot*32;
      const char* pk2 = pk0 + 4096;
      const unsigned want = (unsigned)(t+1);
      int4 r[8];
      while (true){
        r[0] = ld_i4<0>(pk0);    r[1] = ld_i4<16>(pk0);
        r[2] = ld_i4<2048>(pk0); r[3] = ld_i4<2064>(pk0);
        r[4] = ld_i4<0>(pk2);    r[5] = ld_i4<16>(pk2);
        r[6] = ld_i4<2048>(pk2); r[7] = ld_i4<2064>(pk2);
        asm volatile("s_waitcnt vmcnt(0)" ::: "memory");
        __builtin_amdgcn_sched_barrier(0);
        unsigned mn = 0xFFFFFFFFu;
#pragma unroll
        for (int i=0;i<8;i++){
          unsigned t0 = (unsigned)r[i].y, t1 = (unsigned)r[i].w;
          mn = mn < t0 ? mn : t0;
          mn = mn < t1 ? mn : t1;
        }
        if (__all((int)(mn >= want))) break;
      }
      // strip tags, publish quarter to LDS
      s_buf[gslot]       = mk_frag(r[0], r[1]);
      s_buf[gslot + 64]  = mk_frag(r[2], r[3]);
      s_buf[gslot + 128] = mk_frag(r[4], r[5]);
      s_buf[gslot + 192] = mk_frag(r[6], r[7]);
      __syncthreads();
      f32x4 acc0 = 0, acc1 = 0;
#pragma unroll
      for (int kc=0;kc<8;kc++){
        f16x8 a0 = s_buf[kc*128 + fs];
        f16x8 a1 = s_buf[kc*128 + fs + 16];
        acc0 = __builtin_amdgcn_mfma_f32_16x16x32_f16(a0, bf[kc], acc0, 0,0,0);
        acc1 = __builtin_amdgcn_mfma_f32_16x16x32_f16(a1, bf[kc], acc1, 0,0,0);
      }
#pragma unroll
      for (int rr=0;rr<4;rr++){
        s_g[wave][kg*4+rr][lm] = acc0[rr];
        s_g[wave][16+kg*4+rr][lm] = acc1[rr];
      }
      __syncthreads();
      {
        float gi0 = s_g[0][b][kl0] + (float)gv0[0];
        float gi1 = s_g[0][b][kl1] + (float)gv0[1];
        float gf0 = s_g[1][b][kl0] + (float)gv1[0];
        float gf1 = s_g[1][b][kl1] + (float)gv1[1];
        float gc0 = s_g[2][b][kl0] + (float)gv2[0];
        float gc1 = s_g[2][b][kl1] + (float)gv2[1];
        float go0 = s_g[3][b][kl0] + (float)gv3[0];
        float go1 = s_g[3][b][kl1] + (float)gv3[1];
        float cn0 = fast_sigmoid(gf0)*h0 + fast_sigmoid(gi0)*fast_tanh(gc0);  // quirk
        float cn1 = fast_sigmoid(gf1)*h1 + fast_sigmoid(gi1)*fast_tanh(gc1);
        float hn0 = fast_sigmoid(go0)*fast_tanh(cn0);
        float hn1 = fast_sigmoid(go1)*fast_tanh(cn1);
        h0 = hn0; h1 = hn1;
        store_tag(cpubt + ((t&1)<<15) + pu, cn0, cn1, (unsigned)(t+2));
        store_tag(decpt + ((size_t)t<<15) + pu, hn0, hn1, (unsigned)(t+2));
      }
      // no drain, no flag: tags travel with the data
    }
  } else {
    // ---- layer 2 (standard cell, masked freeze)
    const int isl = blockIdx.x - 16;
    const f16* whh2 = (const f16*)(ws + O_WHH2);
    const f16* w2   = (const f16*)(ws + O_W2);
    const f16* gih2 = (const f16*)(ws + O_GIH2C);
    f16x8 bfh[8], bfx[8];
    {
      int j = wave*256 + isl*16 + lm;
#pragma unroll
      for (int kc=0;kc<8;kc++){
        bfh[kc] = *(const f16x8*)(whh2 + j*256 + kc*32 + kg*8);
        bfx[kc] = *(const f16x8*)(w2 + j*512 + kc*32 + kg*8);
      }
    }
    float c0 = 0.f, c1 = 0.f, hh0 = 0.f, hh1 = 0.f;
    const int lenv = inp_len[b];
    const int kk0 = isl*16 + kl0;
    const int pu = ((kk0>>5)*128 + ((kk0>>3)&3)*32 + b)*32 + ((kk0&7)>>1)*8;
    // init: publish h2(-1)=0 with tag 1 into buffer 1
    store_tag(h2pt + 32768 + pu, 0.f, 0.f, 1u);
    for (int t=0;t<512;t++){
      const f16* gp = gih2 + (size_t)(b*512 + t)*1024 + isl*16 + kl0;
      f16x2 gv0 = *(const f16x2*)(gp);
      f16x2 gv1 = *(const f16x2*)(gp+256);
      f16x2 gv2 = *(const f16x2*)(gp+512);
      f16x2 gv3 = *(const f16x2*)(gp+768);
      // merged split poll: this wave's quarter of decp[t] (want t+2) and
      // h2pub[(t+1)&1] (want t+1)
      const char* xb = decpt + ((size_t)t<<15);
      const char* hb = h2pt + (((t+1)&1)<<15);
      const char* px0 = xb + (size_t)gslot*32;
      const char* px2 = px0 + 4096;
      const char* ph0 = hb + (size_t)gslot*32;
      const char* ph2 = ph0 + 4096;
      const unsigned wantx = (unsigned)(t+2);
      const unsigned wanth = (unsigned)(t+1);
      int4 rx[8], rh[8];
      while (true){
        rx[0] = ld_i4<0>(px0);    rx[1] = ld_i4<16>(px0);
        rx[2] = ld_i4<2048>(px0); rx[3] = ld_i4<2064>(px0);
        rx[4] = ld_i4<0>(px2);    rx[5] = ld_i4<16>(px2);
        rx[6] = ld_i4<2048>(px2); rx[7] = ld_i4<2064>(px2);
        rh[0] = ld_i4<0>(ph0);    rh[1] = ld_i4<16>(ph0);
        rh[2] = ld_i4<2048>(ph0); rh[3] = ld_i4<2064>(ph0);
        rh[4] = ld_i4<0>(ph2);    rh[5] = ld_i4<16>(ph2);
        rh[6] = ld_i4<2048>(ph2); rh[7] = ld_i4<2064>(ph2);
        asm volatile("s_waitcnt vmcnt(0)" ::: "memory");
        __builtin_amdgcn_sched_barrier(0);
        unsigned mx = 0xFFFFFFFFu, mh = 0xFFFFFFFFu;
#pragma unroll
        for (int i=0;i<8;i++){
          unsigned a0 = (unsigned)rx[i].y, a1 = (unsigned)rx[i].w;
          mx = mx < a0 ? mx : a0;
          mx = mx < a1 ? mx : a1;
          unsigned b0 = (unsigned)rh[i].y, b1 = (unsigned)rh[i].w;
          mh = mh < b0 ? mh : b0;
          mh = mh < b1 ? mh : b1;
        }
        if (__all((int)((mx >= wantx) & (mh >= wanth)))) break;
      }
      s_buf[gslot]        = mk_frag(rx[0], rx[1]);
      s_buf[gslot + 64]   = mk_frag(rx[2], rx[3]);
      s_buf[gslot + 128]  = mk_frag(rx[4], rx[5]);
      s_buf[gslot + 192]  = mk_frag(rx[6], rx[7]);
      s_buf[1024 + gslot]       = mk_frag(rh[0], rh[1]);
      s_buf[1024 + gslot + 64]  = mk_frag(rh[2], rh[3]);
      s_buf[1024 + gslot + 128] = mk_frag(rh[4], rh[5]);
      s_buf[1024 + gslot + 192] = mk_frag(rh[6], rh[7]);
      __syncthreads();
      f32x4 acc0 = 0, acc1 = 0;
#pragma unroll
      for (int kc=0;kc<8;kc++){
        f16x8 ax0 = s_buf[kc*128 + fs];
        f16x8 ax1 = s_buf[kc*128 + fs + 16];
        f16x8 ah0 = s_buf[1024 + kc*128 + fs];
        f16x8 ah1 = s_buf[1024 + kc*128 + fs + 16];
        acc0 = __builtin_amdgcn_mfma_f32_16x16x32_f16(ax0, bfx[kc], acc0, 0,0,0);
        acc1 = __builtin_amdgcn_mfma_f32_16x16x32_f16(ax1, bfx[kc], acc1, 0,0,0);
        acc0 = __builtin_amdgcn_mfma_f32_16x16x32_f16(ah0, bfh[kc], acc0, 0,0,0);
        acc1 = __builtin_amdgcn_mfma_f32_16x16x32_f16(ah1, bfh[kc], acc1, 0,0,0);
      }
#pragma unroll
      for (int rr=0;rr<4;rr++){
        s_g[wave][kg*4+rr][lm] = acc0[rr];
        s_g[wave][16+kg*4+rr][lm] = acc1[rr];
      }
      __syncthreads();
      float ov0, ov1;
      {
        float gi0 = s_g[0][b][kl0] + (float)gv0[0];
        float gi1 = s_g[0][b][kl1] + (float)gv0[1];
        float gf0 = s_g[1][b][kl0] + (float)gv1[0];
        float gf1 = s_g[1][b][kl1] + (float)gv1[1];
        float gc0 = s_g[2][b][kl0] + (float)gv2[0];
        float gc1 = s_g[2][b][kl1] + (float)gv2[1];
        float go0 = s_g[3][b][kl0] + (float)gv3[0];
        float go1 = s_g[3][b][kl1] + (float)gv3[1];
        float cn0 = fast_sigmoid(gf0)*c0 + fast_sigmoid(gi0)*fast_tanh(gc0);
        float cn1 = fast_sigmoid(gf1)*c1 + fast_sigmoid(gi1)*fast_tanh(gc1);
        float hn0 = fast_sigmoid(go0)*fast_tanh(cn0);
        float hn1 = fast_sigmoid(go1)*fast_tanh(cn1);
        bool valid = (t < lenv);
        c0 = valid ? cn0 : c0;
        c1 = valid ? cn1 : c1;
        hh0 = valid ? hn0 : hh0;
        hh1 = valid ? hn1 : hh1;
        ov0 = valid ? hn0 : 0.f;
        ov1 = valid ? hn1 : 0.f;
        store_tag(h2pt + ((t&1)<<15) + pu, hh0, hh1, (unsigned)(t+2));
      }
      float2 ov; ov.x = ov0; ov.y = ov1;
      *(float2*)(out + (size_t)(b*512 + t)*256 + isl*16 + kl0) = ov;
    }
  }
}

extern "C" void kernel_launch(void* const* d_in, const int* in_sizes, int n_in,
                              void* d_out, int out_size, void* d_ws, size_t ws_size,
                              hipStream_t stream) {
  if (ws_size < WS_NEED) return;  // workspace too small; bail (output stays poison -> visible failure)
  const float* enc    = (const float*)d_in[0];
  const float* bhs    = (const float*)d_in[1];
  const float* bcs    = (const float*)d_in[2];
  const float* attn_W = (const float*)d_in[3];
  const float* attn_b = (const float*)d_in[4];
  const float* attn_V = (const float*)d_in[5];
  const float* l1_Wih = (const float*)d_in[6];
  const float* l1_Whh = (const float*)d_in[7];
  const float* l1_bih = (const float*)d_in[8];
  const float* l1_bhh = (const float*)d_in[9];
  const float* l2_Wih = (const float*)d_in[10];
  const float* l2_Whh = (const float*)d_in[11];
  const float* l2_bih = (const float*)d_in[12];
  const float* l2_bhh = (const float*)d_in[13];
  const int* inp_len  = (const int*)d_in[14];
  char* ws = (char*)d_ws;
  float* out = (float*)d_out;

  prep_kernel<<<6700, 256, 0, stream>>>(attn_W, attn_b, attn_V, l1_Wih, l1_Whh, l1_bih, l1_bhh,
                                        l2_Wih, l2_Whh, l2_bih, l2_bhh, bcs, ws);
  encf_kernel<<<4096, 256, 0, stream>>>(enc, ws);
  // pqv = k2*(enc@Wq^T | enc@Wv^T + b)
  gemm_nt<false><<<dim3(4,128), 256, 0, stream>>>((const f16*)(ws+O_ENCF), nullptr, 256,
        (const f16*)(ws+O_WQV), 256, (void*)(ws+O_PQV), 512, 256, (const float*)(ws+O_BQV));
  score_ctx_kernel<<<dim3(64,32), 256, 0, stream>>>(ws, enc, inp_len);
  // gih1 = [enc|ctx]@W1^T + (bih1+bhh1)
  gemm_nt<true><<<dim3(8,128), 256, 0, stream>>>((const f16*)(ws+O_ENCF), (const f16*)(ws+O_CTX), 256,
        (const f16*)(ws+O_W1), 512, (void*)(ws+O_GIH1), 1024, 512, (const float*)(ws+O_B1));
  // gih2c = ctx@W2R^T + (bih2+bhh2)   (aliases pqv region; pqv dead after score_ctx)
  gemm_nt<true><<<dim3(8,128), 256, 0, stream>>>((const f16*)(ws+O_CTX), nullptr, 256,
        (const f16*)(ws+O_W2)+256, 512, (void*)(ws+O_GIH2C), 1024, 256, (const float*)(ws+O_B2));
  // zero tag regions (CTX/ENCF and WQV are dead after the gemms above)
  hipMemsetAsync(ws + O_DECT, 0, 16777216UL, stream);
  hipMemsetAsync(ws + O_CPUBT, 0, 131072UL, stream);
  rec_kernel<<<32, 256, 0, stream>>>(ws, bhs, bcs, inp_len, out);
}